// Round 5
// baseline (1164.805 us; speedup 1.0000x reference)
//
#include <hip/hip_runtime.h>
#include <math.h>

typedef __attribute__((ext_vector_type(8))) short short8;
typedef __attribute__((ext_vector_type(4))) float f32x4;
typedef __attribute__((ext_vector_type(8))) unsigned short ushort8v;

__device__ __forceinline__ ushort f2bf(float f) {
    unsigned u = __builtin_bit_cast(unsigned, f);
    u = (u + 0x7fffu + ((u >> 16) & 1u)) >> 16;
    return (ushort)u;
}
__device__ __forceinline__ float bf2f(ushort h) {
    unsigned u = ((unsigned)h) << 16;
    return __builtin_bit_cast(float, u);
}

// async global->LDS DMA, 16B per lane. LDS dest is wave-uniform base + lane*16.
__device__ __forceinline__ void cp16(const ushort* g, ushort* l) {
    __builtin_amdgcn_global_load_lds(
        (const __attribute__((address_space(1))) unsigned int*)g,
        (__attribute__((address_space(3))) unsigned int*)l, 16, 0, 0);
}

// counted-vmcnt barrier (T3/T4): keep the newest N DMA loads (those issued in
// THIS phase) in flight across the barrier; retire everything older. lgkmcnt(0)
// guarantees this wave's ds_reads finished before other waves' DMA may
// overwrite the region after the barrier.
#define BARv(N) asm volatile("s_waitcnt vmcnt(" #N ") lgkmcnt(0)\n\ts_barrier" ::: "memory")

// pair-swizzle: ids differing by 8 -> same XCD; map the two m0-halves of a
// tile to {g*16 + x, g*16 + 8 + x} so they share an XCD-L2 (X tile reuse).
__device__ __forceinline__ void pair_decode(int bid, int nt, int& tile, int& mm) {
    int f16 = (nt * 2) & ~15;
    if (bid < f16) { tile = ((bid >> 4) << 3) | (bid & 7); mm = (bid >> 3) & 1; }
    else { int r = bid - f16; tile = (f16 >> 1) + (r >> 1); mm = r & 1; }
}

// ---------------- cast / pack kernels ----------------

// NCHW f32 -> NHWC bf16, 256ch x 32px tile. Loads 128B-coalesced, stores
// 512B-contiguous (128 lanes x ushort2 cover one pixel's 256-ch slice).
__global__ __launch_bounds__(256) void nchw2nhwc(const float* __restrict__ in,
                                                 ushort* __restrict__ out,
                                                 int C, int HW)
{
    __shared__ float tile[256][33];
    const int n  = blockIdx.z;
    const int c0 = blockIdx.y << 8;
    const int p0 = blockIdx.x << 5;
    const float* inp = in + (size_t)n * C * HW + (size_t)c0 * HW + p0;
    const int t = threadIdx.x;
    const int pr = t & 31, cr = t >> 5;
    const bool pok = (p0 + pr) < HW;
    #pragma unroll 8
    for (int i = 0; i < 32; ++i) {
        int c = i * 8 + cr;
        tile[c][pr] = pok ? inp[(size_t)c * HW + pr] : 0.f;
    }
    __syncthreads();
    ushort* op = out + (size_t)n * HW * C + c0;
    const int cp = (t & 127) * 2, ph = t >> 7;
    #pragma unroll 4
    for (int j = 0; j < 16; ++j) {
        int p = j * 2 + ph;
        if (p0 + p < HW) {
            ushort2 v;
            v.x = f2bf(tile[cp][p]);
            v.y = f2bf(tile[cp + 1][p]);
            *(ushort2*)&op[(size_t)(p0 + p) * C + cp] = v;
        }
    }
}

__global__ void cast_k(const float* __restrict__ in, ushort* __restrict__ out, int n)
{
    int i = blockIdx.x * 256 + threadIdx.x;
    if (i < n) out[i] = f2bf(in[i]);
}

// 3x3 weights OIHW f32 -> [co][tap][ci] bf16 (tap-major K)
__global__ void pack_w3(const float* __restrict__ w, ushort* __restrict__ wp, int Cin)
{
    int i = blockIdx.x * 256 + threadIdx.x;
    int total = 256 * Cin * 9;
    if (i >= total) return;
    int co  = i / (9 * Cin);
    int rem = i - co * 9 * Cin;
    int tap = rem / Cin;
    int ci  = rem - tap * Cin;
    wp[i] = f2bf(w[(size_t)co * Cin * 9 + (size_t)ci * 9 + tap]);
}

// zero the 1-px border of a padded [n][Hp][Wp][256] bf16 buffer
__global__ void zero_border(ushort* __restrict__ T, int Hp, int Wp, int NB, int total)
{
    int i = blockIdx.x * 256 + threadIdx.x;
    if (i >= total) return;
    const int cg = (i & 31) * 8;
    const int pb = i >> 5;
    const int n  = pb / NB;
    const int b  = pb - n * NB;
    int y, x;
    if (b < 2 * Wp) { y = (b < Wp) ? 0 : (Hp - 1); x = (b < Wp) ? b : (b - Wp); }
    else { int rem = b - 2 * Wp; y = 1 + (rem >> 1); x = (rem & 1) ? (Wp - 1) : 0; }
    ushort8v z = {0, 0, 0, 0, 0, 0, 0, 0};
    *(ushort8v*)&T[((size_t)n * Hp * Wp + (size_t)y * Wp + x) * 256 + cg] = z;
}

// ---------------- 1x1 MFMA conv (implicit GEMM, NHWC bf16) ----------------
// unchanged proven structure: gload_lds staging, 2 LDS bufs, sync-per-chunk.
template<int PADOUT>
__global__ __launch_bounds__(256, 4) void conv1_mfma(
    const ushort* __restrict__ X, const ushort* __restrict__ Wt,
    const float* __restrict__ bias, ushort* __restrict__ Y,
    int Cin, int H, int Wd, int nP)
{
    const int HW = H * Wd;
    int tile, mm;
    pair_decode(blockIdx.x, nP, tile, mm);
    const int p0 = tile * 128;
    const int m0 = mm << 7;
    const int n  = blockIdx.z;
    const ushort* Xn = X + (size_t)n * HW * Cin;

    const int t    = threadIdx.x;
    const int lane = t & 63;
    const int wave = t >> 6;
    const int l15  = lane & 15, lq = lane >> 4;

    __shared__ __align__(16) ushort smem[17408];

    const int rA  = ((t >> 6) << 4) | (t & 15);
    const int lq8 = ((t >> 4) & 3) * 8;
    const ushort* agA = Wt + (size_t)(m0 + rA) * Cin + lq8;
    const ushort* agB = agA + (size_t)64 * Cin;
    const ushort* XqA = Xn + (size_t)(p0 + rA) * Cin + lq8;
    const ushort* XqB = Xn + (size_t)(p0 + rA + 64) * Cin + lq8;

    const int fr    = (lq * 16 + l15) * 8;
    const int aoff  = ((wave >> 1) * 4) * 512;
    const int boff  = 4096 + ((wave & 1) * 4) * 512;
    const int wbase = wave << 9;

    const int nch = Cin >> 5;

    auto stage = [&](int bb, int c) {
        const int kA = c << 5;
        cp16(agA + kA, &smem[bb + wbase]);
        cp16(agB + kA, &smem[bb + 2048 + wbase]);
        cp16(XqA + kA, &smem[bb + 4096 + wbase]);
        cp16(XqB + kA, &smem[bb + 6144 + wbase]);
    };

    f32x4 acc[4][4] = {};

    stage(0, 0);
    __syncthreads();

    #pragma unroll 1
    for (int c = 0; c < nch; c += 2) {
        {
            stage(8192, c + 1);
            short8 af[4], bf[4];
            #pragma unroll
            for (int mi = 0; mi < 4; ++mi) af[mi] = *(const short8*)&smem[aoff + mi * 512 + fr];
            #pragma unroll
            for (int ni = 0; ni < 4; ++ni) bf[ni] = *(const short8*)&smem[boff + ni * 512 + fr];
            #pragma unroll
            for (int mi = 0; mi < 4; ++mi)
                #pragma unroll
                for (int ni = 0; ni < 4; ++ni)
                    acc[mi][ni] = __builtin_amdgcn_mfma_f32_16x16x32_bf16(
                        af[mi], bf[ni], acc[mi][ni], 0, 0, 0);
            __syncthreads();
        }
        {
            if (c + 2 < nch) stage(0, c + 2);
            short8 af[4], bf[4];
            #pragma unroll
            for (int mi = 0; mi < 4; ++mi) af[mi] = *(const short8*)&smem[8192 + aoff + mi * 512 + fr];
            #pragma unroll
            for (int ni = 0; ni < 4; ++ni) bf[ni] = *(const short8*)&smem[8192 + boff + ni * 512 + fr];
            #pragma unroll
            for (int mi = 0; mi < 4; ++mi)
                #pragma unroll
                for (int ni = 0; ni < 4; ++ni)
                    acc[mi][ni] = __builtin_amdgcn_mfma_f32_16x16x32_bf16(
                        af[mi], bf[ni], acc[mi][ni], 0, 0, 0);
            __syncthreads();
        }
    }

    const int wm = (wave >> 1) * 64, wn = (wave & 1) * 64;
    #pragma unroll
    for (int mi = 0; mi < 4; ++mi) {
        const int co = wm + mi * 16 + lq * 4;
        float4 bv = *(const float4*)&bias[m0 + co];
        float bb4[4] = {bv.x, bv.y, bv.z, bv.w};
        #pragma unroll
        for (int ni = 0; ni < 4; ++ni) {
            const int p = wn + ni * 16 + l15;
            ushort4 h;
            h.x = f2bf(acc[mi][ni][0] + bb4[0]);
            h.y = f2bf(acc[mi][ni][1] + bb4[1]);
            h.z = f2bf(acc[mi][ni][2] + bb4[2]);
            h.w = f2bf(acc[mi][ni][3] + bb4[3]);
            *(ushort4*)&smem[p * 136 + co] = h;
        }
    }
    __syncthreads();

    ushort* Yn = PADOUT ? (Y + (size_t)n * (H + 2) * (Wd + 2) * 256)
                        : (Y + (size_t)n * HW * 256);
    #pragma unroll
    for (int it = 0; it < 8; ++it) {
        int idx = it * 256 + t;
        int px  = idx >> 4;
        int off = (idx & 15) * 8;
        int qq  = p0 + px;
        if (qq >= HW) continue;
        uint4 v = *(const uint4*)&smem[px * 136 + off];
        if (PADOUT) {
            int y = qq / Wd, x = qq - (qq / Wd) * Wd;
            *(uint4*)&Yn[((size_t)(y + 1) * (Wd + 2) + (x + 1)) * 256 + m0 + off] = v;
        } else {
            *(uint4*)&Yn[(size_t)qq * 256 + m0 + off] = v;
        }
    }
}

// ---------------- 3x3 MFMA conv, LDS halo, reg-prefetch pipeline ----------
// Output tile 8x16 px, M=128 co. X padded [n][Hout+2][Wout+2][256], border 0.
// Key change vs r4: fragments for tap p+1 are ds_read into a SECOND register
// set DURING tap p (buffers stable >=2 phases), so MFMA16 consumes registers
// only and the LDS round-trip is off the critical path (8-phase-style
// interleave). A panels: ring of 3, staged distance-3 (tap p stages panel
// p+3 into ring p%3 -- that slot's last LDS readers finished 2 barriers ago;
// the current tap's data is in regs). Panel staged at s is retired by the
// counted barrier at end of s+1 and prefetch-read at s+2 (the r4-proven
// stage/retire/read pattern). B halo dbuf staged taps 1-3, distance 6-8.
__global__ __launch_bounds__(256, 3) void conv3_mfma(
    const ushort* __restrict__ X, const ushort* __restrict__ Wt,
    const float* __restrict__ bias, ushort* __restrict__ Y,
    int Hout, int Wout, int ct, int nt)
{
    const int Wp = Wout + 2;
    int tile, mm;
    pair_decode(blockIdx.x, nt, tile, mm);
    const int ty = tile / ct, tx = tile - ty * ct;
    int y0 = ty * 8;  if (y0 > Hout - 8)  y0 = Hout - 8;
    int x0 = tx * 16; if (x0 > Wout - 16) x0 = Wout - 16;
    const int m0 = mm << 7;
    const int nb = blockIdx.z;
    const ushort* Xn = X + (size_t)nb * (Hout + 2) * Wp * 256;

    const int t    = threadIdx.x;
    const int lane = t & 63;
    const int wave = t >> 6;
    const int l15  = lane & 15, lq = lane >> 4;

    // A rings at 0,4096,8192 | B bufs at 12288, 18048 (5760 each). 47,616 B.
    __shared__ __align__(16) ushort smem[23808];

    const int rA  = ((t >> 6) << 4) | (t & 15);
    const int lq8 = ((t >> 4) & 3) * 8;
    const ushort* agA = Wt + (size_t)(m0 + rA) * 2304 + lq8;
    const ushort* agB = agA + (size_t)64 * 2304;

    const int fra  = (lq * 16 + l15) * 8;
    const int aoff = (wave >> 1) * 2048;
    const int bb   = (((wave & 1) * 16 + lq) * 144) + l15 * 8;  // rel. B base

    auto stageA = [&](int ring, int ccA, int tapA) {
        const int kA = tapA * 256 + (ccA << 5);
        cp16(agA + kA, &smem[ring * 4096 + t * 8]);
        cp16(agB + kA, &smem[ring * 4096 + 2048 + t * 8]);
    };
    // one of 3 rounds of the 720-slot halo for chunk cc into buffer bsel
    auto stageBr = [&](int bsel, int cc, int rnd) {
        const int cb = cc << 5;
        int s = rnd * 256 + t;
        if (s < 720) {
            int py  = s / 72, rem = s - py * 72;
            int lqq = rem / 18, pxc = rem - lqq * 18;
            cp16(Xn + ((size_t)(y0 + py) * Wp + (x0 + pxc)) * 256 + cb + lqq * 8,
                 &smem[12288 + bsel * 5760 + s * 8]);
        }
    };

    f32x4 acc[4][4] = {};
    short8 af0[4], bf0[4], af1[4], bf1[4];

// read the frags of tap (RING, BSEL, DY, DX) into register set S
#define PREFETCH(S, RING, BSEL, DY, DX)                                           \
    {                                                                             \
        _Pragma("unroll")                                                         \
        for (int mi = 0; mi < 4; ++mi)                                            \
            af##S[mi] = *(const short8*)&smem[(RING) * 4096 + aoff + mi * 512 + fra];\
        _Pragma("unroll")                                                         \
        for (int ni = 0; ni < 4; ++ni)                                            \
            bf##S[ni] = *(const short8*)&smem[12288 + (BSEL) * 5760 + bb          \
                                              + (ni + (DY)) * 576 + (DX) * 8];    \
    }
#define MFMA16(S)                                                                 \
    __builtin_amdgcn_s_setprio(1);                                                \
    _Pragma("unroll")                                                             \
    for (int mi = 0; mi < 4; ++mi)                                                \
        _Pragma("unroll")                                                         \
        for (int ni = 0; ni < 4; ++ni)                                            \
            acc[mi][ni] = __builtin_amdgcn_mfma_f32_16x16x32_bf16(                \
                af##S[mi], bf##S[ni], acc[mi][ni], 0, 0, 0);                      \
    __builtin_amdgcn_s_setprio(0);

// one 9-tap chunk. E/O = register-set ids for even/odd taps (literal 0/1).
// CB/NB = B buf of current/next chunk (literal 0/1). cc/ccn runtime ints.
// tap p: stage A panel (cc,p+3) into ring p%3 (spills into ccn taps 0-2);
//        prefetch frags of tap p+1; MFMA on regs loaded last phase.
#define CHUNK(cc, ccn, CB, NB, E, O)                                               \
    stageA(0, cc, 3);                             PREFETCH(O, 1, CB, 0, 1); MFMA16(E); BARv(2); \
    stageA(1, cc, 4); stageBr(NB, ccn, 0);        PREFETCH(E, 2, CB, 0, 2); MFMA16(O); BARv(3); \
    stageA(2, cc, 5); stageBr(NB, ccn, 1);        PREFETCH(O, 0, CB, 1, 0); MFMA16(E); BARv(3); \
    stageA(0, cc, 6); stageBr(NB, ccn, 2);        PREFETCH(E, 1, CB, 1, 1); MFMA16(O); BARv(3); \
    stageA(1, cc, 7);                             PREFETCH(O, 2, CB, 1, 2); MFMA16(E); BARv(2); \
    stageA(2, cc, 8);                             PREFETCH(E, 0, CB, 2, 0); MFMA16(O); BARv(2); \
    stageA(0, ccn, 0);                            PREFETCH(O, 1, CB, 2, 1); MFMA16(E); BARv(2); \
    stageA(1, ccn, 1);                            PREFETCH(E, 2, CB, 2, 2); MFMA16(O); BARv(2); \
    stageA(2, ccn, 2);                            PREFETCH(O, 0, NB, 0, 0); MFMA16(E); BARv(2);

    // prologue: B(chunk0)->buf0; A panels taps 0,1,2 -> rings 0,1,2; drain;
    // then read tap0's frags into set0 (compiler inserts the lgkm wait).
    stageBr(0, 0, 0); stageBr(0, 0, 1); stageBr(0, 0, 2);
    stageA(0, 0, 0);
    stageA(1, 0, 1);
    stageA(2, 0, 2);
    __syncthreads();
    PREFETCH(0, 0, 0, 0, 0);

    #pragma unroll 1
    for (int cp = 0; cp < 4; ++cp) {
        const int cc = 2 * cp, c1 = 2 * cp + 1;
        const int c2 = (cp < 3) ? 2 * cp + 2 : 7;   // clamp: uniform counts
        CHUNK(cc, c1, 0, 1, 0, 1);
        CHUNK(c1, c2, 1, 0, 1, 0);
    }
#undef CHUNK
#undef MFMA16
#undef PREFETCH
    __syncthreads();   // drains remaining DMA + lgkm before smem reuse

    // epilogue: stage via LDS for 256B-contiguous stores
    const int wm = (wave >> 1) * 64, wn = (wave & 1) * 64;
    #pragma unroll
    for (int mi = 0; mi < 4; ++mi) {
        const int co = wm + mi * 16 + lq * 4;
        float4 bv = *(const float4*)&bias[m0 + co];
        float bb4[4] = {bv.x, bv.y, bv.z, bv.w};
        #pragma unroll
        for (int ni = 0; ni < 4; ++ni) {
            const int p = wn + ni * 16 + l15;
            ushort4 h;
            h.x = f2bf(acc[mi][ni][0] + bb4[0]);
            h.y = f2bf(acc[mi][ni][1] + bb4[1]);
            h.z = f2bf(acc[mi][ni][2] + bb4[2]);
            h.w = f2bf(acc[mi][ni][3] + bb4[3]);
            *(ushort4*)&smem[p * 136 + co] = h;
        }
    }
    __syncthreads();

    ushort* Yn = Y + (size_t)nb * Hout * Wout * 256;
    #pragma unroll
    for (int it = 0; it < 8; ++it) {
        int idx = it * 256 + t;
        int p   = idx >> 4;
        int off = (idx & 15) * 8;
        int yy  = y0 + (p >> 4), xx = x0 + (p & 15);
        *(uint4*)&Yn[((size_t)yy * Wout + xx) * 256 + m0 + off] =
            *(const uint4*)&smem[p * 136 + off];
    }
}

// ---------------- upsample(2x bilinear, half-pixel, clamp) + add ----------------
// T is PADDED [n][H+2][Wd+2][256]; Pn (coarser level) is unpadded.
__global__ void upsample_add_nhwc(ushort* __restrict__ T, const ushort* __restrict__ Pn,
                                  int H, int Wd, int total32)
{
    int i = blockIdx.x * 256 + threadIdx.x;
    if (i >= total32) return;
    const int cg = (i & 31) * 8;
    const int q  = i >> 5;
    const int HW = H * Wd;
    const int n   = q / HW;
    const int pix = q - n * HW;
    const int y = pix / Wd, x = pix - (pix / Wd) * Wd;
    const int Hh = H >> 1, Wh = Wd >> 1;

    float sy = fminf(fmaxf(y * 0.5f - 0.25f, 0.f), (float)(Hh - 1));
    float sx = fminf(fmaxf(x * 0.5f - 0.25f, 0.f), (float)(Wh - 1));
    int y0 = (int)sy, x0 = (int)sx;
    int y1 = min(y0 + 1, Hh - 1), x1 = min(x0 + 1, Wh - 1);
    float fy = sy - (float)y0, fx = sx - (float)x0;

    const ushort* base = Pn + (size_t)n * Hh * Wh * 256 + cg;
    ushort8v a00 = *(const ushort8v*)&base[(size_t)(y0 * Wh + x0) * 256];
    ushort8v a01 = *(const ushort8v*)&base[(size_t)(y0 * Wh + x1) * 256];
    ushort8v a10 = *(const ushort8v*)&base[(size_t)(y1 * Wh + x0) * 256];
    ushort8v a11 = *(const ushort8v*)&base[(size_t)(y1 * Wh + x1) * 256];

    const int Wp2 = Wd + 2;
    ushort* tp = T + ((size_t)n * (H + 2) * Wp2 + (size_t)(y + 1) * Wp2 + (x + 1)) * 256 + cg;
    ushort8v tv = *(ushort8v*)tp;
    ushort8v r;
    #pragma unroll
    for (int j = 0; j < 8; ++j) {
        float v = (1.f - fy) * ((1.f - fx) * bf2f(a00[j]) + fx * bf2f(a01[j]))
                +        fy  * ((1.f - fx) * bf2f(a10[j]) + fx * bf2f(a11[j]));
        r[j] = f2bf(bf2f(tv[j]) + v);
    }
    *(ushort8v*)tp = r;
}

// ---------------- roi align (NHWC bf16 feats, f32 out) ----------------
__global__ __launch_bounds__(256) void roi_align_k(
    const float* __restrict__ rois, const float* __restrict__ im_info,
    const ushort* __restrict__ p2, const ushort* __restrict__ p3,
    const ushort* __restrict__ p4, const ushort* __restrict__ p5,
    float* __restrict__ out)
{
    const int r   = blockIdx.x;
    const int tid = threadIdx.x;

    __shared__ int   s_y0[14], s_y1[14], s_x0[14], s_x1[14];
    __shared__ float s_ly[14], s_lx[14], s_vy[14], s_vx[14];
    __shared__ float s_o[256 * 49];

    const float bx  = rois[r * 5 + 0];
    const float x1r = rois[r * 5 + 1];
    const float y1r = rois[r * 5 + 2];
    const float x2r = rois[r * 5 + 3];
    const float y2r = rois[r * 5 + 4];

    const float hh = y2r - y1r + 1.f;
    const float ww = x2r - x1r + 1.f;
    float lf = rintf(logf(sqrtf(hh * ww) * (1.f / 224.f)) + 4.f);
    lf = fminf(fmaxf(lf, 2.f), 5.f);
    const int lvl = (int)lf;

    const ushort* feat; int H, W;
    if      (lvl == 2) { feat = p2; H = 200; W = 304; }
    else if (lvl == 3) { feat = p3; H = 100; W = 152; }
    else if (lvl == 4) { feat = p4; H = 50;  W = 76;  }
    else               { feat = p5; H = 25;  W = 38;  }

    const float im_h  = im_info[0];
    const float scale = (float)H / im_h;
    const float x1 = x1r * scale, y1 = y1r * scale;
    const float x2 = x2r * scale, y2 = y2r * scale;
    const float rw = fmaxf(x2 - x1, 1.f);
    const float rh = fmaxf(y2 - y1, 1.f);
    const float bh = rh * (1.f / 7.f);
    const float bw = rw * (1.f / 7.f);

    if (tid < 28) {
        if (tid < 14) {
            int i = tid, pi = i >> 1, s = i & 1;
            float ys = y1 + pi * bh + (s + 0.5f) * bh * 0.5f;
            float v  = (ys >= -1.f && ys <= (float)H) ? 1.f : 0.f;
            float yc = fminf(fmaxf(ys, 0.f), (float)H - 1.f);
            int y0 = (int)floorf(yc);
            s_y0[i] = y0; s_y1[i] = min(y0 + 1, H - 1);
            s_ly[i] = yc - (float)y0; s_vy[i] = v;
        } else {
            int i = tid - 14, pi = i >> 1, s = i & 1;
            float xs = x1 + pi * bw + (s + 0.5f) * bw * 0.5f;
            float v  = (xs >= -1.f && xs <= (float)W) ? 1.f : 0.f;
            float xc = fminf(fmaxf(xs, 0.f), (float)W - 1.f);
            int x0 = (int)floorf(xc);
            s_x0[i] = x0; s_x1[i] = min(x0 + 1, W - 1);
            s_lx[i] = xc - (float)x0; s_vx[i] = v;
        }
    }
    __syncthreads();

    const int b = (int)bx;
    const ushort* fc = feat + (size_t)b * H * W * 256 + tid;

    #pragma unroll
    for (int py = 0; py < 7; ++py) {
        #pragma unroll
        for (int px = 0; px < 7; ++px) {
            float acc = 0.f;
            #pragma unroll
            for (int sy = 0; sy < 2; ++sy) {
                #pragma unroll
                for (int sx = 0; sx < 2; ++sx) {
                    int iy = py * 2 + sy, ix = px * 2 + sx;
                    float ly = s_ly[iy], lx = s_lx[ix];
                    float hy = 1.f - ly, hx = 1.f - lx;
                    int y0 = s_y0[iy], y1i = s_y1[iy];
                    int x0 = s_x0[ix], x1i = s_x1[ix];
                    float v00 = bf2f(fc[(size_t)(y0 * W + x0) * 256]);
                    float v01 = bf2f(fc[(size_t)(y0 * W + x1i) * 256]);
                    float v10 = bf2f(fc[(size_t)(y1i * W + x0) * 256]);
                    float v11 = bf2f(fc[(size_t)(y1i * W + x1i) * 256]);
                    float val = hy * hx * v00 + hy * lx * v01
                              + ly * hx * v10 + ly * lx * v11;
                    acc += val * s_vy[iy] * s_vx[ix];
                }
            }
            s_o[tid * 49 + py * 7 + px] = acc * 0.25f;
        }
    }
    __syncthreads();
    float* orow = out + (size_t)r * 256 * 49;
    for (int it = 0; it < 49; ++it)
        orow[it * 256 + tid] = s_o[it * 256 + tid];
}

static inline int cdiv(int a, int b) { return (a + b - 1) / b; }

extern "C" void kernel_launch(void* const* d_in, const int* in_sizes, int n_in,
                              void* d_out, int out_size, void* d_ws, size_t ws_size,
                              hipStream_t stream) {
    const float* c2      = (const float*)d_in[0];
    const float* c3      = (const float*)d_in[1];
    const float* c4      = (const float*)d_in[2];
    const float* c5      = (const float*)d_in[3];
    const float* rois    = (const float*)d_in[4];
    const float* im_info = (const float*)d_in[5];
    const float* w_top   = (const float*)d_in[6];
    const float* b_top   = (const float*)d_in[7];
    const float* w_lat1  = (const float*)d_in[8];
    const float* b_lat1  = (const float*)d_in[9];
    const float* w_lat2  = (const float*)d_in[10];
    const float* b_lat2  = (const float*)d_in[11];
    const float* w_lat3  = (const float*)d_in[12];
    const float* b_lat3  = (const float*)d_in[13];
    const float* w_sm1   = (const float*)d_in[14];
    const float* b_sm1   = (const float*)d_in[15];
    const float* w_sm2   = (const float*)d_in[16];
    const float* b_sm2   = (const float*)d_in[17];
    const float* w_sm3   = (const float*)d_in[18];
    const float* b_sm3   = (const float*)d_in[19];
    float* out = (float*)d_out;
    ushort* ws = (ushort*)d_ws;

    // workspace layout (bf16 elements, all 16B-aligned).
    // T is PADDED: max level2 = 2*202*306*256. p2 aliases c2t (dead by then).
    ushort* c2t = ws;                      // 2*60800*256 = 31129600
    ushort* c3t = c2t + 31129600;          // 2*15200*512 = 15564800
    ushort* c4t = c3t + 15564800;          // 2*3800*1024 = 7782400
    ushort* c5t = c4t + 7782400;           // 2*950*2048  = 3891200
    ushort* p5  = c5t + 3891200;           // 2*950*256   = 486400
    ushort* p4  = p5  + 486400;            // 2*3800*256  = 1945600
    ushort* p3  = p4  + 1945600;           // 2*15200*256 = 7782400
    ushort* T   = p3  + 7782400;           // 2*202*306*256 = 31647744 (padded)
    ushort* wtp = T   + 31647744;          // 256*2048
    ushort* wl1 = wtp + 524288;            // 256*1024
    ushort* wl2 = wl1 + 262144;            // 256*512
    ushort* wl3 = wl2 + 131072;            // 256*256
    ushort* ws1 = wl3 + 65536;             // 256*2304
    ushort* ws2 = ws1 + 589824;
    ushort* ws3 = ws2 + 589824;
    ushort* p2  = c2t;                     // alias (c2t consumed before p2 write)

    dim3 blk(256);

    // pack weights
    cast_k<<<cdiv(524288, 256), blk, 0, stream>>>(w_top,  wtp, 524288);
    cast_k<<<cdiv(262144, 256), blk, 0, stream>>>(w_lat1, wl1, 262144);
    cast_k<<<cdiv(131072, 256), blk, 0, stream>>>(w_lat2, wl2, 131072);
    cast_k<<<cdiv(65536,  256), blk, 0, stream>>>(w_lat3, wl3, 65536);
    pack_w3<<<cdiv(589824, 256), blk, 0, stream>>>(w_sm1, ws1, 256);
    pack_w3<<<cdiv(589824, 256), blk, 0, stream>>>(w_sm2, ws2, 256);
    pack_w3<<<cdiv(589824, 256), blk, 0, stream>>>(w_sm3, ws3, 256);

    // transpose inputs to NHWC bf16 (256ch x 32px tiles)
    nchw2nhwc<<<dim3(1900, 1, 2), blk, 0, stream>>>(c2, c2t, 256,  60800);
    nchw2nhwc<<<dim3(475,  2, 2), blk, 0, stream>>>(c3, c3t, 512,  15200);
    nchw2nhwc<<<dim3(119,  4, 2), blk, 0, stream>>>(c4, c4t, 1024, 3800);
    nchw2nhwc<<<dim3(30,   8, 2), blk, 0, stream>>>(c5, c5t, 2048, 950);

    // p5 = conv1x1(c5)   (unpadded output)
    conv1_mfma<0><<<dim3(16, 1, 2), blk, 0, stream>>>(c5t, wtp, b_top, p5, 2048, 25, 38, 8);

    // level 4: lat -> padded T(52x78), border zero, upsample-add, 3x3 -> p4
    conv1_mfma<1><<<dim3(60, 1, 2), blk, 0, stream>>>(c4t, wl1, b_lat1, T, 1024, 50, 76, 30);
    zero_border<<<cdiv(16384, 256), blk, 0, stream>>>(T, 52, 78, 256, 16384);
    upsample_add_nhwc<<<cdiv(2 * 3800 * 32, 256), blk, 0, stream>>>(T, p5, 50, 76, 2 * 3800 * 32);
    conv3_mfma<<<dim3(70, 1, 2), blk, 0, stream>>>(T, ws1, b_sm1, p4, 50, 76, 5, 35);

    // level 3
    conv1_mfma<1><<<dim3(238, 1, 2), blk, 0, stream>>>(c3t, wl2, b_lat2, T, 512, 100, 152, 119);
    zero_border<<<cdiv(32512, 256), blk, 0, stream>>>(T, 102, 154, 508, 32512);
    upsample_add_nhwc<<<cdiv(2 * 15200 * 32, 256), blk, 0, stream>>>(T, p4, 100, 152, 2 * 15200 * 32);
    conv3_mfma<<<dim3(260, 1, 2), blk, 0, stream>>>(T, ws2, b_sm2, p3, 100, 152, 10, 130);

    // level 2
    conv1_mfma<1><<<dim3(950, 1, 2), blk, 0, stream>>>(c2t, wl3, b_lat3, T, 256, 200, 304, 475);
    zero_border<<<cdiv(64768, 256), blk, 0, stream>>>(T, 202, 306, 1012, 64768);
    upsample_add_nhwc<<<cdiv(2 * 60800 * 32, 256), blk, 0, stream>>>(T, p3, 200, 304, 2 * 60800 * 32);
    conv3_mfma<<<dim3(950, 1, 2), blk, 0, stream>>>(T, ws3, b_sm3, p2, 200, 304, 19, 475);

    // roi align
    roi_align_k<<<dim3(1024), blk, 0, stream>>>(rois, im_info, p2, p3, p4, p5, out);
}

// Round 8
// 1018.678 us; speedup vs baseline: 1.1434x; 1.1434x over previous
//
#include <hip/hip_runtime.h>
#include <math.h>

typedef __attribute__((ext_vector_type(8))) short short8;
typedef __attribute__((ext_vector_type(4))) float f32x4;
typedef __attribute__((ext_vector_type(8))) unsigned short ushort8v;

__device__ __forceinline__ ushort f2bf(float f) {
    unsigned u = __builtin_bit_cast(unsigned, f);
    u = (u + 0x7fffu + ((u >> 16) & 1u)) >> 16;
    return (ushort)u;
}
__device__ __forceinline__ float bf2f(ushort h) {
    unsigned u = ((unsigned)h) << 16;
    return __builtin_bit_cast(float, u);
}

// async global->LDS DMA, 16B per lane. LDS dest is wave-uniform base + lane*16.
__device__ __forceinline__ void cp16(const ushort* g, ushort* l) {
    __builtin_amdgcn_global_load_lds(
        (const __attribute__((address_space(1))) unsigned int*)g,
        (__attribute__((address_space(3))) unsigned int*)l, 16, 0, 0);
}

// pair-swizzle: ids differing by 8 -> same XCD; map the two m0-halves of a
// tile to {g*16 + x, g*16 + 8 + x} so they share an XCD-L2 (X tile reuse).
__device__ __forceinline__ void pair_decode(int bid, int nt, int& tile, int& mm) {
    int f16 = (nt * 2) & ~15;
    if (bid < f16) { tile = ((bid >> 4) << 3) | (bid & 7); mm = (bid >> 3) & 1; }
    else { int r = bid - f16; tile = (f16 >> 1) + (r >> 1); mm = r & 1; }
}

// ---------------- fused pack + border-zero kernel (one launch) -------------
// blockIdx.y: 0-3 = f32->bf16 weight casts, 4-6 = 3x3 weight repack
// (OIHW f32 -> [co][tap][ci] bf16), 7-9 = zero the 1-px border of T4/T3/T2.
__global__ __launch_bounds__(256) void pack_zero_k(
    const float* __restrict__ w_top,  const float* __restrict__ w_lat1,
    const float* __restrict__ w_lat2, const float* __restrict__ w_lat3,
    const float* __restrict__ w_sm1,  const float* __restrict__ w_sm2,
    const float* __restrict__ w_sm3,
    ushort* __restrict__ wtp, ushort* __restrict__ wl1,
    ushort* __restrict__ wl2, ushort* __restrict__ wl3,
    ushort* __restrict__ ws1, ushort* __restrict__ ws2, ushort* __restrict__ ws3,
    ushort* __restrict__ T4, ushort* __restrict__ T3, ushort* __restrict__ T2)
{
    const int j = blockIdx.y;
    const int i = blockIdx.x * 256 + threadIdx.x;
    if (j < 4) {
        const float* src; ushort* dst; int n;
        if      (j == 0) { src = w_top;  dst = wtp; n = 524288; }
        else if (j == 1) { src = w_lat1; dst = wl1; n = 262144; }
        else if (j == 2) { src = w_lat2; dst = wl2; n = 131072; }
        else             { src = w_lat3; dst = wl3; n = 65536;  }
        if (i < n) dst[i] = f2bf(src[i]);
    } else if (j < 7) {
        const float* src; ushort* dst;
        if      (j == 4) { src = w_sm1; dst = ws1; }
        else if (j == 5) { src = w_sm2; dst = ws2; }
        else             { src = w_sm3; dst = ws3; }
        if (i < 589824) {
            int co  = i / 2304;
            int rem = i - co * 2304;
            int tap = rem >> 8;
            int ci  = rem & 255;
            dst[i] = f2bf(src[(size_t)co * 2304 + (size_t)ci * 9 + tap]);
        }
    } else {
        ushort* Tb; int Hp, Wp, NB, total;
        if      (j == 7) { Tb = T4; Hp = 52;  Wp = 78;  NB = 256;  total = 16384; }
        else if (j == 8) { Tb = T3; Hp = 102; Wp = 154; NB = 508;  total = 32512; }
        else             { Tb = T2; Hp = 202; Wp = 306; NB = 1012; total = 64768; }
        if (i < total) {
            const int cg = (i & 31) * 8;
            const int pb = i >> 5;
            const int n  = pb / NB;
            const int b  = pb - n * NB;
            int y, x;
            if (b < 2 * Wp) { y = (b < Wp) ? 0 : (Hp - 1); x = (b < Wp) ? b : (b - Wp); }
            else { int rem = b - 2 * Wp; y = 1 + (rem >> 1); x = (rem & 1) ? (Wp - 1) : 0; }
            ushort8v z = {0, 0, 0, 0, 0, 0, 0, 0};
            *(ushort8v*)&Tb[((size_t)n * Hp * Wp + (size_t)y * Wp + x) * 256 + cg] = z;
        }
    }
}

// ---------------- fused NCHW f32 -> NHWC bf16 transpose (all levels) -------
// 256ch x 32px tile; loads 128B-coalesced, stores 512B-contiguous.
__global__ __launch_bounds__(256) void nchw2nhwc_all(
    const float* __restrict__ c2, const float* __restrict__ c3,
    const float* __restrict__ c4, const float* __restrict__ c5,
    ushort* __restrict__ c2t, ushort* __restrict__ c3t,
    ushort* __restrict__ c4t, ushort* __restrict__ c5t)
{
    __shared__ float tile[256][33];
    const int idx = blockIdx.x;
    const float* in; ushort* out; int C, HW, tx, cy;
    if (idx < 1900)      { in = c2; out = c2t; C = 256;  HW = 60800; tx = idx; cy = 0; }
    else if (idx < 2850) { int l = idx - 1900; in = c3; out = c3t; C = 512;  HW = 15200; tx = l % 475; cy = l / 475; }
    else if (idx < 3326) { int l = idx - 2850; in = c4; out = c4t; C = 1024; HW = 3800;  tx = l % 119; cy = l / 119; }
    else                 { int l = idx - 3326; in = c5; out = c5t; C = 2048; HW = 950;   tx = l % 30;  cy = l / 30;  }
    const int n  = blockIdx.z;
    const int c0 = cy << 8;
    const int p0 = tx << 5;
    const float* inp = in + (size_t)n * C * HW + (size_t)c0 * HW + p0;
    const int t = threadIdx.x;
    const int pr = t & 31, cr = t >> 5;
    const bool pok = (p0 + pr) < HW;
    #pragma unroll 8
    for (int i = 0; i < 32; ++i) {
        int c = i * 8 + cr;
        tile[c][pr] = pok ? inp[(size_t)c * HW + pr] : 0.f;
    }
    __syncthreads();
    ushort* op = out + (size_t)n * HW * C + c0;
    const int cp = (t & 127) * 2, ph = t >> 7;
    #pragma unroll 4
    for (int j = 0; j < 16; ++j) {
        int p = j * 2 + ph;
        if (p0 + p < HW) {
            ushort2 v;
            v.x = f2bf(tile[cp][p]);
            v.y = f2bf(tile[cp + 1][p]);
            *(ushort2*)&op[(size_t)(p0 + p) * C + cp] = v;
        }
    }
}

// ---------------- 1x1 MFMA conv (implicit GEMM, NHWC bf16) ----------------
// gload_lds staging, 2 LDS bufs, sync-per-chunk (proven structure).
// UPADD==0: plain unpadded output (p5).
// UPADD==1: output into padded (H+2)x(W+2) interior of T, ADDING the 2x
// bilinear upsample of Pn (coarse level, unpadded NHWC) -- fuses the
// upsample_add pass into the epilogue (saves a full T RMW + a launch).
template<int UPADD>
__global__ __launch_bounds__(256, 4) void conv1_mfma(
    const ushort* __restrict__ X, const ushort* __restrict__ Wt,
    const float* __restrict__ bias, ushort* __restrict__ Y,
    const ushort* __restrict__ Pn,
    int Cin, int H, int Wd, int nP)
{
    const int HW = H * Wd;
    int tile, mm;
    pair_decode(blockIdx.x, nP, tile, mm);
    const int p0 = tile * 128;
    const int m0 = mm << 7;
    const int n  = blockIdx.z;
    const ushort* Xn = X + (size_t)n * HW * Cin;

    const int t    = threadIdx.x;
    const int lane = t & 63;
    const int wave = t >> 6;
    const int l15  = lane & 15, lq = lane >> 4;

    __shared__ __align__(16) ushort smem[17408];

    const int rA  = ((t >> 6) << 4) | (t & 15);
    const int lq8 = ((t >> 4) & 3) * 8;
    const ushort* agA = Wt + (size_t)(m0 + rA) * Cin + lq8;
    const ushort* agB = agA + (size_t)64 * Cin;
    const ushort* XqA = Xn + (size_t)(p0 + rA) * Cin + lq8;
    const ushort* XqB = Xn + (size_t)(p0 + rA + 64) * Cin + lq8;

    const int fr    = (lq * 16 + l15) * 8;
    const int aoff  = ((wave >> 1) * 4) * 512;
    const int boff  = 4096 + ((wave & 1) * 4) * 512;
    const int wbase = wave << 9;

    const int nch = Cin >> 5;

    auto stage = [&](int bb, int c) {
        const int kA = c << 5;
        cp16(agA + kA, &smem[bb + wbase]);
        cp16(agB + kA, &smem[bb + 2048 + wbase]);
        cp16(XqA + kA, &smem[bb + 4096 + wbase]);
        cp16(XqB + kA, &smem[bb + 6144 + wbase]);
    };

    f32x4 acc[4][4] = {};

    stage(0, 0);
    __syncthreads();

    #pragma unroll 1
    for (int c = 0; c < nch; c += 2) {
        {
            stage(8192, c + 1);
            short8 af[4], bf[4];
            #pragma unroll
            for (int mi = 0; mi < 4; ++mi) af[mi] = *(const short8*)&smem[aoff + mi * 512 + fr];
            #pragma unroll
            for (int ni = 0; ni < 4; ++ni) bf[ni] = *(const short8*)&smem[boff + ni * 512 + fr];
            #pragma unroll
            for (int mi = 0; mi < 4; ++mi)
                #pragma unroll
                for (int ni = 0; ni < 4; ++ni)
                    acc[mi][ni] = __builtin_amdgcn_mfma_f32_16x16x32_bf16(
                        af[mi], bf[ni], acc[mi][ni], 0, 0, 0);
            __syncthreads();
        }
        {
            if (c + 2 < nch) stage(0, c + 2);
            short8 af[4], bf[4];
            #pragma unroll
            for (int mi = 0; mi < 4; ++mi) af[mi] = *(const short8*)&smem[8192 + aoff + mi * 512 + fr];
            #pragma unroll
            for (int ni = 0; ni < 4; ++ni) bf[ni] = *(const short8*)&smem[8192 + boff + ni * 512 + fr];
            #pragma unroll
            for (int mi = 0; mi < 4; ++mi)
                #pragma unroll
                for (int ni = 0; ni < 4; ++ni)
                    acc[mi][ni] = __builtin_amdgcn_mfma_f32_16x16x32_bf16(
                        af[mi], bf[ni], acc[mi][ni], 0, 0, 0);
            __syncthreads();
        }
    }

    const int wm = (wave >> 1) * 64, wn = (wave & 1) * 64;
    #pragma unroll
    for (int mi = 0; mi < 4; ++mi) {
        const int co = wm + mi * 16 + lq * 4;
        float4 bv = *(const float4*)&bias[m0 + co];
        float bb4[4] = {bv.x, bv.y, bv.z, bv.w};
        #pragma unroll
        for (int ni = 0; ni < 4; ++ni) {
            const int p = wn + ni * 16 + l15;
            ushort4 h;
            h.x = f2bf(acc[mi][ni][0] + bb4[0]);
            h.y = f2bf(acc[mi][ni][1] + bb4[1]);
            h.z = f2bf(acc[mi][ni][2] + bb4[2]);
            h.w = f2bf(acc[mi][ni][3] + bb4[3]);
            *(ushort4*)&smem[p * 136 + co] = h;
        }
    }
    __syncthreads();

    ushort* Yn = UPADD ? (Y + (size_t)n * (H + 2) * (Wd + 2) * 256)
                       : (Y + (size_t)n * HW * 256);
    #pragma unroll
    for (int it = 0; it < 8; ++it) {
        int idx = it * 256 + t;
        int px  = idx >> 4;
        int off = (idx & 15) * 8;
        int qq  = p0 + px;
        if (qq >= HW) continue;
        uint4 v = *(const uint4*)&smem[px * 136 + off];
        if (UPADD) {
            const int yq = qq / Wd, xq = qq - (qq / Wd) * Wd;
            const int Hh = H >> 1, Wh = Wd >> 1;
            float sy = fminf(fmaxf(yq * 0.5f - 0.25f, 0.f), (float)(Hh - 1));
            float sx = fminf(fmaxf(xq * 0.5f - 0.25f, 0.f), (float)(Wh - 1));
            int y0 = (int)sy, x0 = (int)sx;
            int y1 = min(y0 + 1, Hh - 1), x1 = min(x0 + 1, Wh - 1);
            float fy = sy - (float)y0, fx = sx - (float)x0;
            const ushort* base = Pn + (size_t)n * Hh * Wh * 256 + m0 + off;
            ushort8v a00 = *(const ushort8v*)&base[(size_t)(y0 * Wh + x0) * 256];
            ushort8v a01 = *(const ushort8v*)&base[(size_t)(y0 * Wh + x1) * 256];
            ushort8v a10 = *(const ushort8v*)&base[(size_t)(y1 * Wh + x0) * 256];
            ushort8v a11 = *(const ushort8v*)&base[(size_t)(y1 * Wh + x1) * 256];
            ushort8v tv = __builtin_bit_cast(ushort8v, v);
            ushort8v r;
            #pragma unroll
            for (int jj = 0; jj < 8; ++jj) {
                float up = (1.f - fy) * ((1.f - fx) * bf2f(a00[jj]) + fx * bf2f(a01[jj]))
                         +        fy  * ((1.f - fx) * bf2f(a10[jj]) + fx * bf2f(a11[jj]));
                r[jj] = f2bf(bf2f(tv[jj]) + up);
            }
            *(uint4*)&Yn[((size_t)(yq + 1) * (Wd + 2) + (xq + 1)) * 256 + m0 + off] =
                __builtin_bit_cast(uint4, r);
        } else {
            *(uint4*)&Yn[(size_t)qq * 256 + m0 + off] = v;
        }
    }
}

// ---------------- 3x3 MFMA conv with LDS halo (round-2 proven version) -----
// Output tile 8x16 px, M=128 co. X padded [n][Hout+2][Wout+2][256], border 0.
// K-loop: 8 ci-chunks x 9 taps. Per ci-chunk one B-halo stage (10x18x32ci)
// serves all 9 taps via uniform LDS offsets; per tap-step one A-panel stage.
__global__ __launch_bounds__(256, 4) void conv3_mfma(
    const ushort* __restrict__ X, const ushort* __restrict__ Wt,
    const float* __restrict__ bias, ushort* __restrict__ Y,
    int Hout, int Wout, int ct, int nt)
{
    const int Wp = Wout + 2;
    int tile, mm;
    pair_decode(blockIdx.x, nt, tile, mm);
    const int ty = tile / ct, tx = tile - ty * ct;
    int y0 = ty * 8;  if (y0 > Hout - 8)  y0 = Hout - 8;
    int x0 = tx * 16; if (x0 > Wout - 16) x0 = Wout - 16;
    const int m0 = mm << 7;
    const int nb = blockIdx.z;
    const ushort* Xn = X + (size_t)nb * (Hout + 2) * Wp * 256;

    const int t    = threadIdx.x;
    const int lane = t & 63;
    const int wave = t >> 6;
    const int l15  = lane & 15, lq = lane >> 4;

    // A0 [0,4096) | A1 [4096,8192) | B0 [8192,13952) | B1 [13952,19712)
    __shared__ __align__(16) ushort smem[19712];
    const int A0o = 0, A1o = 4096, B0o = 8192, B1o = 13952;

    const int rA  = ((t >> 6) << 4) | (t & 15);
    const int lq8 = ((t >> 4) & 3) * 8;
    const ushort* agA = Wt + (size_t)(m0 + rA) * 2304 + lq8;
    const ushort* agB = agA + (size_t)64 * 2304;

    const int fr   = (lq * 16 + l15) * 8;
    const int aoff = (wave >> 1) * 2048;
    const int bb   = (((wave & 1) * 16 + lq) * 144) + l15 * 8;

    auto stageA = [&](int ab, int cc, int tap) {
        const int kA = tap * 256 + (cc << 5);
        cp16(agA + kA, &smem[ab + t * 8]);
        cp16(agB + kA, &smem[ab + 2048 + t * 8]);
    };
    auto stageB = [&](int bbuf, int cc) {
        const int cb = cc << 5;
        #pragma unroll
        for (int rnd = 0; rnd < 3; ++rnd) {
            int s = rnd * 256 + t;
            if (s < 720) {
                int py  = s / 72, rem = s - py * 72;
                int lqq = rem / 18, pxc = rem - lqq * 18;
                cp16(Xn + ((size_t)(y0 + py) * Wp + (x0 + pxc)) * 256 + cb + lqq * 8,
                     &smem[bbuf + s * 8]);
            }
        }
    };

    f32x4 acc[4][4] = {};

    stageB(B0o, 0);
    stageA(A0o, 0, 0);
    __syncthreads();

    #pragma unroll 1
    for (int cc = 0; cc < 8; ++cc) {
        const int pb = cc & 1;
        const int Bb = pb ? B1o : B0o;
        #pragma unroll
        for (int tap = 0; tap < 9; ++tap) {
            const int pa = pb ^ (tap & 1);
            const int Ab = pa ? A1o : A0o;
            const int An = pa ? A0o : A1o;
            if (tap < 8) stageA(An, cc, tap + 1);
            else if (cc < 7) { stageB(pb ? B0o : B1o, cc + 1); stageA(An, cc + 1, 0); }
            const int dy = tap / 3, dx = tap - dy * 3;   // compile-time (unrolled)
            short8 af[4], bf[4];
            #pragma unroll
            for (int mi = 0; mi < 4; ++mi) af[mi] = *(const short8*)&smem[Ab + aoff + mi * 512 + fr];
            #pragma unroll
            for (int ni = 0; ni < 4; ++ni) bf[ni] = *(const short8*)&smem[Bb + bb + (ni + dy) * 576 + dx * 8];
            #pragma unroll
            for (int mi = 0; mi < 4; ++mi)
                #pragma unroll
                for (int ni = 0; ni < 4; ++ni)
                    acc[mi][ni] = __builtin_amdgcn_mfma_f32_16x16x32_bf16(
                        af[mi], bf[ni], acc[mi][ni], 0, 0, 0);
            __syncthreads();
        }
    }

    // epilogue
    const int wm = (wave >> 1) * 64, wn = (wave & 1) * 64;
    #pragma unroll
    for (int mi = 0; mi < 4; ++mi) {
        const int co = wm + mi * 16 + lq * 4;
        float4 bv = *(const float4*)&bias[m0 + co];
        float bb4[4] = {bv.x, bv.y, bv.z, bv.w};
        #pragma unroll
        for (int ni = 0; ni < 4; ++ni) {
            const int p = wn + ni * 16 + l15;
            ushort4 h;
            h.x = f2bf(acc[mi][ni][0] + bb4[0]);
            h.y = f2bf(acc[mi][ni][1] + bb4[1]);
            h.z = f2bf(acc[mi][ni][2] + bb4[2]);
            h.w = f2bf(acc[mi][ni][3] + bb4[3]);
            *(ushort4*)&smem[p * 136 + co] = h;
        }
    }
    __syncthreads();

    ushort* Yn = Y + (size_t)nb * Hout * Wout * 256;
    #pragma unroll
    for (int it = 0; it < 8; ++it) {
        int idx = it * 256 + t;
        int p   = idx >> 4;
        int off = (idx & 15) * 8;
        int yy  = y0 + (p >> 4), xx = x0 + (p & 15);
        *(uint4*)&Yn[((size_t)yy * Wout + xx) * 256 + m0 + off] =
            *(const uint4*)&smem[p * 136 + off];
    }
}

// ---------------- roi align (NHWC bf16 feats, f32 out) ----------------
__global__ __launch_bounds__(256) void roi_align_k(
    const float* __restrict__ rois, const float* __restrict__ im_info,
    const ushort* __restrict__ p2, const ushort* __restrict__ p3,
    const ushort* __restrict__ p4, const ushort* __restrict__ p5,
    float* __restrict__ out)
{
    const int r   = blockIdx.x;
    const int tid = threadIdx.x;

    __shared__ int   s_y0[14], s_y1[14], s_x0[14], s_x1[14];
    __shared__ float s_ly[14], s_lx[14], s_vy[14], s_vx[14];
    __shared__ float s_o[256 * 49];

    const float bx  = rois[r * 5 + 0];
    const float x1r = rois[r * 5 + 1];
    const float y1r = rois[r * 5 + 2];
    const float x2r = rois[r * 5 + 3];
    const float y2r = rois[r * 5 + 4];

    const float hh = y2r - y1r + 1.f;
    const float ww = x2r - x1r + 1.f;
    float lf = rintf(logf(sqrtf(hh * ww) * (1.f / 224.f)) + 4.f);
    lf = fminf(fmaxf(lf, 2.f), 5.f);
    const int lvl = (int)lf;

    const ushort* feat; int H, W;
    if      (lvl == 2) { feat = p2; H = 200; W = 304; }
    else if (lvl == 3) { feat = p3; H = 100; W = 152; }
    else if (lvl == 4) { feat = p4; H = 50;  W = 76;  }
    else               { feat = p5; H = 25;  W = 38;  }

    const float im_h  = im_info[0];
    const float scale = (float)H / im_h;
    const float x1 = x1r * scale, y1 = y1r * scale;
    const float x2 = x2r * scale, y2 = y2r * scale;
    const float rw = fmaxf(x2 - x1, 1.f);
    const float rh = fmaxf(y2 - y1, 1.f);
    const float bh = rh * (1.f / 7.f);
    const float bw = rw * (1.f / 7.f);

    if (tid < 28) {
        if (tid < 14) {
            int i = tid, pi = i >> 1, s = i & 1;
            float ys = y1 + pi * bh + (s + 0.5f) * bh * 0.5f;
            float v  = (ys >= -1.f && ys <= (float)H) ? 1.f : 0.f;
            float yc = fminf(fmaxf(ys, 0.f), (float)H - 1.f);
            int y0 = (int)floorf(yc);
            s_y0[i] = y0; s_y1[i] = min(y0 + 1, H - 1);
            s_ly[i] = yc - (float)y0; s_vy[i] = v;
        } else {
            int i = tid - 14, pi = i >> 1, s = i & 1;
            float xs = x1 + pi * bw + (s + 0.5f) * bw * 0.5f;
            float v  = (xs >= -1.f && xs <= (float)W) ? 1.f : 0.f;
            float xc = fminf(fmaxf(xs, 0.f), (float)W - 1.f);
            int x0 = (int)floorf(xc);
            s_x0[i] = x0; s_x1[i] = min(x0 + 1, W - 1);
            s_lx[i] = xc - (float)x0; s_vx[i] = v;
        }
    }
    __syncthreads();

    const int b = (int)bx;
    const ushort* fc = feat + (size_t)b * H * W * 256 + tid;

    #pragma unroll
    for (int py = 0; py < 7; ++py) {
        #pragma unroll
        for (int px = 0; px < 7; ++px) {
            float acc = 0.f;
            #pragma unroll
            for (int sy = 0; sy < 2; ++sy) {
                #pragma unroll
                for (int sx = 0; sx < 2; ++sx) {
                    int iy = py * 2 + sy, ix = px * 2 + sx;
                    float ly = s_ly[iy], lx = s_lx[ix];
                    float hy = 1.f - ly, hx = 1.f - lx;
                    int y0 = s_y0[iy], y1i = s_y1[iy];
                    int x0 = s_x0[ix], x1i = s_x1[ix];
                    float v00 = bf2f(fc[(size_t)(y0 * W + x0) * 256]);
                    float v01 = bf2f(fc[(size_t)(y0 * W + x1i) * 256]);
                    float v10 = bf2f(fc[(size_t)(y1i * W + x0) * 256]);
                    float v11 = bf2f(fc[(size_t)(y1i * W + x1i) * 256]);
                    float val = hy * hx * v00 + hy * lx * v01
                              + ly * hx * v10 + ly * lx * v11;
                    acc += val * s_vy[iy] * s_vx[ix];
                }
            }
            s_o[tid * 49 + py * 7 + px] = acc * 0.25f;
        }
    }
    __syncthreads();
    float* orow = out + (size_t)r * 256 * 49;
    for (int it = 0; it < 49; ++it)
        orow[it * 256 + tid] = s_o[it * 256 + tid];
}

static inline int cdiv(int a, int b) { return (a + b - 1) / b; }

extern "C" void kernel_launch(void* const* d_in, const int* in_sizes, int n_in,
                              void* d_out, int out_size, void* d_ws, size_t ws_size,
                              hipStream_t stream) {
    const float* c2      = (const float*)d_in[0];
    const float* c3      = (const float*)d_in[1];
    const float* c4      = (const float*)d_in[2];
    const float* c5      = (const float*)d_in[3];
    const float* rois    = (const float*)d_in[4];
    const float* im_info = (const float*)d_in[5];
    const float* w_top   = (const float*)d_in[6];
    const float* b_top   = (const float*)d_in[7];
    const float* w_lat1  = (const float*)d_in[8];
    const float* b_lat1  = (const float*)d_in[9];
    const float* w_lat2  = (const float*)d_in[10];
    const float* b_lat2  = (const float*)d_in[11];
    const float* w_lat3  = (const float*)d_in[12];
    const float* b_lat3  = (const float*)d_in[13];
    const float* w_sm1   = (const float*)d_in[14];
    const float* b_sm1   = (const float*)d_in[15];
    const float* w_sm2   = (const float*)d_in[16];
    const float* b_sm2   = (const float*)d_in[17];
    const float* w_sm3   = (const float*)d_in[18];
    const float* b_sm3   = (const float*)d_in[19];
    float* out = (float*)d_out;
    ushort* ws = (ushort*)d_ws;

    // workspace layout (bf16 elements, all 16B-aligned). Per-level padded T
    // buffers (borders zeroed once, up front). p2 aliases c2t (dead by then).
    ushort* c2t = ws;                      // 2*60800*256  = 31129600
    ushort* c3t = c2t + 31129600;          // 2*15200*512  = 15564800
    ushort* c4t = c3t + 15564800;          // 2*3800*1024  = 7782400
    ushort* c5t = c4t + 7782400;           // 2*950*2048   = 3891200
    ushort* p5  = c5t + 3891200;           // 2*950*256    = 486400
    ushort* p4  = p5  + 486400;            // 2*3800*256   = 1945600
    ushort* p3  = p4  + 1945600;           // 2*15200*256  = 7782400
    ushort* T2  = p3  + 7782400;           // 2*202*306*256 = 31647744
    ushort* T3  = T2  + 31647744;          // 2*102*154*256 = 8042496
    ushort* T4  = T3  + 8042496;           // 2*52*78*256   = 2076672
    ushort* wtp = T4  + 2076672;           // 524288
    ushort* wl1 = wtp + 524288;            // 262144
    ushort* wl2 = wl1 + 262144;            // 131072
    ushort* wl3 = wl2 + 131072;            // 65536
    ushort* ws1 = wl3 + 65536;             // 589824
    ushort* ws2 = ws1 + 589824;            // 589824
    ushort* ws3 = ws2 + 589824;            // 589824
    ushort* p2  = c2t;                     // alias (c2t consumed before p2 write)

    dim3 blk(256);

    // 1: all weight packs + all border zeros
    pack_zero_k<<<dim3(2304, 10), blk, 0, stream>>>(
        w_top, w_lat1, w_lat2, w_lat3, w_sm1, w_sm2, w_sm3,
        wtp, wl1, wl2, wl3, ws1, ws2, ws3, T4, T3, T2);

    // 2: all input transposes
    nchw2nhwc_all<<<dim3(3566, 1, 2), blk, 0, stream>>>(
        c2, c3, c4, c5, c2t, c3t, c4t, c5t);

    // 3: p5 = conv1x1(c5)
    conv1_mfma<0><<<dim3(16, 1, 2), blk, 0, stream>>>(c5t, wtp, b_top, p5, (const ushort*)0, 2048, 25, 38, 8);

    // 4-5: level 4 (lat+upsample fused -> padded T4, 3x3 -> p4)
    conv1_mfma<1><<<dim3(60, 1, 2), blk, 0, stream>>>(c4t, wl1, b_lat1, T4, p5, 1024, 50, 76, 30);
    conv3_mfma<<<dim3(70, 1, 2), blk, 0, stream>>>(T4, ws1, b_sm1, p4, 50, 76, 5, 35);

    // 6-7: level 3
    conv1_mfma<1><<<dim3(238, 1, 2), blk, 0, stream>>>(c3t, wl2, b_lat2, T3, p4, 512, 100, 152, 119);
    conv3_mfma<<<dim3(260, 1, 2), blk, 0, stream>>>(T3, ws2, b_sm2, p3, 100, 152, 10, 130);

    // 8-9: level 2
    conv1_mfma<1><<<dim3(950, 1, 2), blk, 0, stream>>>(c2t, wl3, b_lat3, T2, p3, 256, 200, 304, 475);
    conv3_mfma<<<dim3(950, 1, 2), blk, 0, stream>>>(T2, ws3, b_sm3, p2, 200, 304, 19, 475);

    // 10: roi align
    roi_align_k<<<dim3(1024), blk, 0, stream>>>(rois, im_info, p2, p3, p4, p5, out);
}

// Round 9
// 879.460 us; speedup vs baseline: 1.3245x; 1.1583x over previous
//
#include <hip/hip_runtime.h>
#include <math.h>

typedef __attribute__((ext_vector_type(8))) short short8;
typedef __attribute__((ext_vector_type(4))) float f32x4;
typedef __attribute__((ext_vector_type(8))) unsigned short ushort8v;

__device__ __forceinline__ ushort f2bf(float f) {
    unsigned u = __builtin_bit_cast(unsigned, f);
    u = (u + 0x7fffu + ((u >> 16) & 1u)) >> 16;
    return (ushort)u;
}
__device__ __forceinline__ float bf2f(ushort h) {
    unsigned u = ((unsigned)h) << 16;
    return __builtin_bit_cast(float, u);
}

// async global->LDS DMA, 16B per lane. LDS dest is wave-uniform base + lane*16.
__device__ __forceinline__ void cp16(const ushort* g, ushort* l) {
    __builtin_amdgcn_global_load_lds(
        (const __attribute__((address_space(1))) unsigned int*)g,
        (__attribute__((address_space(3))) unsigned int*)l, 16, 0, 0);
}

// pair-swizzle: ids differing by 8 -> same XCD; map the two m0-halves of a
// tile to {g*16 + x, g*16 + 8 + x} so they share an XCD-L2 (X tile reuse).
__device__ __forceinline__ void pair_decode(int bid, int nt, int& tile, int& mm) {
    int f16 = (nt * 2) & ~15;
    if (bid < f16) { tile = ((bid >> 4) << 3) | (bid & 7); mm = (bid >> 3) & 1; }
    else { int r = bid - f16; tile = (f16 >> 1) + (r >> 1); mm = r & 1; }
}

// ---------------- fused pack + border-zero kernel (one launch) -------------
// blockIdx.y: 0-3 = f32->bf16 weight casts, 4-6 = 3x3 weight repack
// (OIHW f32 -> [co][tap][ci] bf16), 7-9 = zero the 1-px border of T4/T3/T2.
__global__ __launch_bounds__(256) void pack_zero_k(
    const float* __restrict__ w_top,  const float* __restrict__ w_lat1,
    const float* __restrict__ w_lat2, const float* __restrict__ w_lat3,
    const float* __restrict__ w_sm1,  const float* __restrict__ w_sm2,
    const float* __restrict__ w_sm3,
    ushort* __restrict__ wtp, ushort* __restrict__ wl1,
    ushort* __restrict__ wl2, ushort* __restrict__ wl3,
    ushort* __restrict__ ws1, ushort* __restrict__ ws2, ushort* __restrict__ ws3,
    ushort* __restrict__ T4, ushort* __restrict__ T3, ushort* __restrict__ T2)
{
    const int j = blockIdx.y;
    const int i = blockIdx.x * 256 + threadIdx.x;
    if (j < 4) {
        const float* src; ushort* dst; int n;
        if      (j == 0) { src = w_top;  dst = wtp; n = 524288; }
        else if (j == 1) { src = w_lat1; dst = wl1; n = 262144; }
        else if (j == 2) { src = w_lat2; dst = wl2; n = 131072; }
        else             { src = w_lat3; dst = wl3; n = 65536;  }
        if (i < n) dst[i] = f2bf(src[i]);
    } else if (j < 7) {
        const float* src; ushort* dst;
        if      (j == 4) { src = w_sm1; dst = ws1; }
        else if (j == 5) { src = w_sm2; dst = ws2; }
        else             { src = w_sm3; dst = ws3; }
        if (i < 589824) {
            int co  = i / 2304;
            int rem = i - co * 2304;
            int tap = rem >> 8;
            int ci  = rem & 255;
            dst[i] = f2bf(src[(size_t)co * 2304 + (size_t)ci * 9 + tap]);
        }
    } else {
        ushort* Tb; int Hp, Wp, NB, total;
        if      (j == 7) { Tb = T4; Hp = 52;  Wp = 78;  NB = 256;  total = 16384; }
        else if (j == 8) { Tb = T3; Hp = 102; Wp = 154; NB = 508;  total = 32512; }
        else             { Tb = T2; Hp = 202; Wp = 306; NB = 1012; total = 64768; }
        if (i < total) {
            const int cg = (i & 31) * 8;
            const int pb = i >> 5;
            const int n  = pb / NB;
            const int b  = pb - n * NB;
            int y, x;
            if (b < 2 * Wp) { y = (b < Wp) ? 0 : (Hp - 1); x = (b < Wp) ? b : (b - Wp); }
            else { int rem = b - 2 * Wp; y = 1 + (rem >> 1); x = (rem & 1) ? (Wp - 1) : 0; }
            ushort8v z = {0, 0, 0, 0, 0, 0, 0, 0};
            *(ushort8v*)&Tb[((size_t)n * Hp * Wp + (size_t)y * Wp + x) * 256 + cg] = z;
        }
    }
}

// ---------------- fused NCHW f32 -> NHWC bf16 transpose (all levels) -------
// 256ch x 32px tile; loads 128B-coalesced, stores 512B-contiguous.
__global__ __launch_bounds__(256) void nchw2nhwc_all(
    const float* __restrict__ c2, const float* __restrict__ c3,
    const float* __restrict__ c4, const float* __restrict__ c5,
    ushort* __restrict__ c2t, ushort* __restrict__ c3t,
    ushort* __restrict__ c4t, ushort* __restrict__ c5t)
{
    __shared__ float tile[256][33];
    const int idx = blockIdx.x;
    const float* in; ushort* out; int C, HW, tx, cy;
    if (idx < 1900)      { in = c2; out = c2t; C = 256;  HW = 60800; tx = idx; cy = 0; }
    else if (idx < 2850) { int l = idx - 1900; in = c3; out = c3t; C = 512;  HW = 15200; tx = l % 475; cy = l / 475; }
    else if (idx < 3326) { int l = idx - 2850; in = c4; out = c4t; C = 1024; HW = 3800;  tx = l % 119; cy = l / 119; }
    else                 { int l = idx - 3326; in = c5; out = c5t; C = 2048; HW = 950;   tx = l % 30;  cy = l / 30;  }
    const int n  = blockIdx.z;
    const int c0 = cy << 8;
    const int p0 = tx << 5;
    const float* inp = in + (size_t)n * C * HW + (size_t)c0 * HW + p0;
    const int t = threadIdx.x;
    const int pr = t & 31, cr = t >> 5;
    const bool pok = (p0 + pr) < HW;
    #pragma unroll 8
    for (int i = 0; i < 32; ++i) {
        int c = i * 8 + cr;
        tile[c][pr] = pok ? inp[(size_t)c * HW + pr] : 0.f;
    }
    __syncthreads();
    ushort* op = out + (size_t)n * HW * C + c0;
    const int cp = (t & 127) * 2, ph = t >> 7;
    #pragma unroll 4
    for (int j = 0; j < 16; ++j) {
        int p = j * 2 + ph;
        if (p0 + p < HW) {
            ushort2 v;
            v.x = f2bf(tile[cp][p]);
            v.y = f2bf(tile[cp + 1][p]);
            *(ushort2*)&op[(size_t)(p0 + p) * C + cp] = v;
        }
    }
}

// ---------------- 1x1 MFMA conv (implicit GEMM, NHWC bf16) ----------------
// gload_lds staging, 2 LDS bufs, sync-per-chunk (proven structure).
// UPADD==0: plain unpadded output (p5).
// UPADD==1: output into padded (H+2)x(W+2) interior of T, ADDING the 2x
// bilinear upsample of Pn (coarse level, unpadded NHWC).
template<int UPADD>
__global__ __launch_bounds__(256, 4) void conv1_mfma(
    const ushort* __restrict__ X, const ushort* __restrict__ Wt,
    const float* __restrict__ bias, ushort* __restrict__ Y,
    const ushort* __restrict__ Pn,
    int Cin, int H, int Wd, int nP)
{
    const int HW = H * Wd;
    int tile, mm;
    pair_decode(blockIdx.x, nP, tile, mm);
    const int p0 = tile * 128;
    const int m0 = mm << 7;
    const int n  = blockIdx.z;
    const ushort* Xn = X + (size_t)n * HW * Cin;

    const int t    = threadIdx.x;
    const int lane = t & 63;
    const int wave = t >> 6;
    const int l15  = lane & 15, lq = lane >> 4;

    __shared__ __align__(16) ushort smem[17408];

    const int rA  = ((t >> 6) << 4) | (t & 15);
    const int lq8 = ((t >> 4) & 3) * 8;
    const ushort* agA = Wt + (size_t)(m0 + rA) * Cin + lq8;
    const ushort* agB = agA + (size_t)64 * Cin;
    const ushort* XqA = Xn + (size_t)(p0 + rA) * Cin + lq8;
    const ushort* XqB = Xn + (size_t)(p0 + rA + 64) * Cin + lq8;

    const int fr    = (lq * 16 + l15) * 8;
    const int aoff  = ((wave >> 1) * 4) * 512;
    const int boff  = 4096 + ((wave & 1) * 4) * 512;
    const int wbase = wave << 9;

    const int nch = Cin >> 5;

    auto stage = [&](int bb, int c) {
        const int kA = c << 5;
        cp16(agA + kA, &smem[bb + wbase]);
        cp16(agB + kA, &smem[bb + 2048 + wbase]);
        cp16(XqA + kA, &smem[bb + 4096 + wbase]);
        cp16(XqB + kA, &smem[bb + 6144 + wbase]);
    };

    f32x4 acc[4][4] = {};

    stage(0, 0);
    __syncthreads();

    #pragma unroll 1
    for (int c = 0; c < nch; c += 2) {
        {
            stage(8192, c + 1);
            short8 af[4], bf[4];
            #pragma unroll
            for (int mi = 0; mi < 4; ++mi) af[mi] = *(const short8*)&smem[aoff + mi * 512 + fr];
            #pragma unroll
            for (int ni = 0; ni < 4; ++ni) bf[ni] = *(const short8*)&smem[boff + ni * 512 + fr];
            #pragma unroll
            for (int mi = 0; mi < 4; ++mi)
                #pragma unroll
                for (int ni = 0; ni < 4; ++ni)
                    acc[mi][ni] = __builtin_amdgcn_mfma_f32_16x16x32_bf16(
                        af[mi], bf[ni], acc[mi][ni], 0, 0, 0);
            __syncthreads();
        }
        {
            if (c + 2 < nch) stage(0, c + 2);
            short8 af[4], bf[4];
            #pragma unroll
            for (int mi = 0; mi < 4; ++mi) af[mi] = *(const short8*)&smem[8192 + aoff + mi * 512 + fr];
            #pragma unroll
            for (int ni = 0; ni < 4; ++ni) bf[ni] = *(const short8*)&smem[8192 + boff + ni * 512 + fr];
            #pragma unroll
            for (int mi = 0; mi < 4; ++mi)
                #pragma unroll
                for (int ni = 0; ni < 4; ++ni)
                    acc[mi][ni] = __builtin_amdgcn_mfma_f32_16x16x32_bf16(
                        af[mi], bf[ni], acc[mi][ni], 0, 0, 0);
            __syncthreads();
        }
    }

    const int wm = (wave >> 1) * 64, wn = (wave & 1) * 64;
    #pragma unroll
    for (int mi = 0; mi < 4; ++mi) {
        const int co = wm + mi * 16 + lq * 4;
        float4 bv = *(const float4*)&bias[m0 + co];
        float bb4[4] = {bv.x, bv.y, bv.z, bv.w};
        #pragma unroll
        for (int ni = 0; ni < 4; ++ni) {
            const int p = wn + ni * 16 + l15;
            ushort4 h;
            h.x = f2bf(acc[mi][ni][0] + bb4[0]);
            h.y = f2bf(acc[mi][ni][1] + bb4[1]);
            h.z = f2bf(acc[mi][ni][2] + bb4[2]);
            h.w = f2bf(acc[mi][ni][3] + bb4[3]);
            *(ushort4*)&smem[p * 136 + co] = h;
        }
    }
    __syncthreads();

    ushort* Yn = UPADD ? (Y + (size_t)n * (H + 2) * (Wd + 2) * 256)
                       : (Y + (size_t)n * HW * 256);
    #pragma unroll
    for (int it = 0; it < 8; ++it) {
        int idx = it * 256 + t;
        int px  = idx >> 4;
        int off = (idx & 15) * 8;
        int qq  = p0 + px;
        if (qq >= HW) continue;
        uint4 v = *(const uint4*)&smem[px * 136 + off];
        if (UPADD) {
            const int yq = qq / Wd, xq = qq - (qq / Wd) * Wd;
            const int Hh = H >> 1, Wh = Wd >> 1;
            float sy = fminf(fmaxf(yq * 0.5f - 0.25f, 0.f), (float)(Hh - 1));
            float sx = fminf(fmaxf(xq * 0.5f - 0.25f, 0.f), (float)(Wh - 1));
            int y0 = (int)sy, x0 = (int)sx;
            int y1 = min(y0 + 1, Hh - 1), x1 = min(x0 + 1, Wh - 1);
            float fy = sy - (float)y0, fx = sx - (float)x0;
            const ushort* base = Pn + (size_t)n * Hh * Wh * 256 + m0 + off;
            ushort8v a00 = *(const ushort8v*)&base[(size_t)(y0 * Wh + x0) * 256];
            ushort8v a01 = *(const ushort8v*)&base[(size_t)(y0 * Wh + x1) * 256];
            ushort8v a10 = *(const ushort8v*)&base[(size_t)(y1 * Wh + x0) * 256];
            ushort8v a11 = *(const ushort8v*)&base[(size_t)(y1 * Wh + x1) * 256];
            ushort8v tv = __builtin_bit_cast(ushort8v, v);
            ushort8v r;
            #pragma unroll
            for (int jj = 0; jj < 8; ++jj) {
                float up = (1.f - fy) * ((1.f - fx) * bf2f(a00[jj]) + fx * bf2f(a01[jj]))
                         +        fy  * ((1.f - fx) * bf2f(a10[jj]) + fx * bf2f(a11[jj]));
                r[jj] = f2bf(bf2f(tv[jj]) + up);
            }
            *(uint4*)&Yn[((size_t)(yq + 1) * (Wd + 2) + (xq + 1)) * 256 + m0 + off] =
                __builtin_bit_cast(uint4, r);
        } else {
            *(uint4*)&Yn[(size_t)qq * 256 + m0 + off] = v;
        }
    }
}

// ---------------- 3x3 MFMA conv with LDS halo (round-2 proven version) -----
// Output tile 8x16 px, M=128 co. X padded [n][Hout+2][Wout+2][256], border 0.
// K-loop: 8 ci-chunks x 9 taps. Per ci-chunk one B-halo stage (10x18x32ci)
// serves all 9 taps via uniform LDS offsets; per tap-step one A-panel stage.
__global__ __launch_bounds__(256, 4) void conv3_mfma(
    const ushort* __restrict__ X, const ushort* __restrict__ Wt,
    const float* __restrict__ bias, ushort* __restrict__ Y,
    int Hout, int Wout, int ct, int nt)
{
    const int Wp = Wout + 2;
    int tile, mm;
    pair_decode(blockIdx.x, nt, tile, mm);
    const int ty = tile / ct, tx = tile - ty * ct;
    int y0 = ty * 8;  if (y0 > Hout - 8)  y0 = Hout - 8;
    int x0 = tx * 16; if (x0 > Wout - 16) x0 = Wout - 16;
    const int m0 = mm << 7;
    const int nb = blockIdx.z;
    const ushort* Xn = X + (size_t)nb * (Hout + 2) * Wp * 256;

    const int t    = threadIdx.x;
    const int lane = t & 63;
    const int wave = t >> 6;
    const int l15  = lane & 15, lq = lane >> 4;

    // A0 [0,4096) | A1 [4096,8192) | B0 [8192,13952) | B1 [13952,19712)
    __shared__ __align__(16) ushort smem[19712];
    const int A0o = 0, A1o = 4096, B0o = 8192, B1o = 13952;

    const int rA  = ((t >> 6) << 4) | (t & 15);
    const int lq8 = ((t >> 4) & 3) * 8;
    const ushort* agA = Wt + (size_t)(m0 + rA) * 2304 + lq8;
    const ushort* agB = agA + (size_t)64 * 2304;

    const int fr   = (lq * 16 + l15) * 8;
    const int aoff = (wave >> 1) * 2048;
    const int bb   = (((wave & 1) * 16 + lq) * 144) + l15 * 8;

    auto stageA = [&](int ab, int cc, int tap) {
        const int kA = tap * 256 + (cc << 5);
        cp16(agA + kA, &smem[ab + t * 8]);
        cp16(agB + kA, &smem[ab + 2048 + t * 8]);
    };
    auto stageB = [&](int bbuf, int cc) {
        const int cb = cc << 5;
        #pragma unroll
        for (int rnd = 0; rnd < 3; ++rnd) {
            int s = rnd * 256 + t;
            if (s < 720) {
                int py  = s / 72, rem = s - py * 72;
                int lqq = rem / 18, pxc = rem - lqq * 18;
                cp16(Xn + ((size_t)(y0 + py) * Wp + (x0 + pxc)) * 256 + cb + lqq * 8,
                     &smem[bbuf + s * 8]);
            }
        }
    };

    f32x4 acc[4][4] = {};

    stageB(B0o, 0);
    stageA(A0o, 0, 0);
    __syncthreads();

    #pragma unroll 1
    for (int cc = 0; cc < 8; ++cc) {
        const int pb = cc & 1;
        const int Bb = pb ? B1o : B0o;
        #pragma unroll
        for (int tap = 0; tap < 9; ++tap) {
            const int pa = pb ^ (tap & 1);
            const int Ab = pa ? A1o : A0o;
            const int An = pa ? A0o : A1o;
            if (tap < 8) stageA(An, cc, tap + 1);
            else if (cc < 7) { stageB(pb ? B0o : B1o, cc + 1); stageA(An, cc + 1, 0); }
            const int dy = tap / 3, dx = tap - dy * 3;   // compile-time (unrolled)
            short8 af[4], bf[4];
            #pragma unroll
            for (int mi = 0; mi < 4; ++mi) af[mi] = *(const short8*)&smem[Ab + aoff + mi * 512 + fr];
            #pragma unroll
            for (int ni = 0; ni < 4; ++ni) bf[ni] = *(const short8*)&smem[Bb + bb + (ni + dy) * 576 + dx * 8];
            #pragma unroll
            for (int mi = 0; mi < 4; ++mi)
                #pragma unroll
                for (int ni = 0; ni < 4; ++ni)
                    acc[mi][ni] = __builtin_amdgcn_mfma_f32_16x16x32_bf16(
                        af[mi], bf[ni], acc[mi][ni], 0, 0, 0);
            __syncthreads();
        }
    }

    // epilogue
    const int wm = (wave >> 1) * 64, wn = (wave & 1) * 64;
    #pragma unroll
    for (int mi = 0; mi < 4; ++mi) {
        const int co = wm + mi * 16 + lq * 4;
        float4 bv = *(const float4*)&bias[m0 + co];
        float bb4[4] = {bv.x, bv.y, bv.z, bv.w};
        #pragma unroll
        for (int ni = 0; ni < 4; ++ni) {
            const int p = wn + ni * 16 + l15;
            ushort4 h;
            h.x = f2bf(acc[mi][ni][0] + bb4[0]);
            h.y = f2bf(acc[mi][ni][1] + bb4[1]);
            h.z = f2bf(acc[mi][ni][2] + bb4[2]);
            h.w = f2bf(acc[mi][ni][3] + bb4[3]);
            *(ushort4*)&smem[p * 136 + co] = h;
        }
    }
    __syncthreads();

    ushort* Yn = Y + (size_t)nb * Hout * Wout * 256;
    #pragma unroll
    for (int it = 0; it < 8; ++it) {
        int idx = it * 256 + t;
        int p   = idx >> 4;
        int off = (idx & 15) * 8;
        int yy  = y0 + (p >> 4), xx = x0 + (p & 15);
        *(uint4*)&Yn[((size_t)yy * Wout + xx) * 256 + m0 + off] =
            *(const uint4*)&smem[p * 136 + off];
    }
}

// ---------------- roi align (NHWC bf16 feats, f32 out) ----------------
// Vectorized: 256 threads = 64 channel-groups (ushort4, 8B/lane -> 512B
// contiguous per wave-read) x 4 parallel bin-groups. 3.8x fewer load issues
// than the scalar-per-channel version. Output staged via LDS [bin][ch]
// (lane-consecutive 16B stores) then coalesced f32 copy.
__global__ __launch_bounds__(256) void roi_align_k(
    const float* __restrict__ rois, const float* __restrict__ im_info,
    const ushort* __restrict__ p2, const ushort* __restrict__ p3,
    const ushort* __restrict__ p4, const ushort* __restrict__ p5,
    float* __restrict__ out)
{
    const int r   = blockIdx.x;
    const int tid = threadIdx.x;

    __shared__ int   s_y0[14], s_y1[14], s_x0[14], s_x1[14];
    __shared__ float s_ly[14], s_lx[14], s_vy[14], s_vx[14];
    __shared__ float s_o[49 * 260];   // [bin][ch], 260-f32 row (16B-aligned)

    const float bx  = rois[r * 5 + 0];
    const float x1r = rois[r * 5 + 1];
    const float y1r = rois[r * 5 + 2];
    const float x2r = rois[r * 5 + 3];
    const float y2r = rois[r * 5 + 4];

    const float hh = y2r - y1r + 1.f;
    const float ww = x2r - x1r + 1.f;
    float lf = rintf(logf(sqrtf(hh * ww) * (1.f / 224.f)) + 4.f);
    lf = fminf(fmaxf(lf, 2.f), 5.f);
    const int lvl = (int)lf;

    const ushort* feat; int H, W;
    if      (lvl == 2) { feat = p2; H = 200; W = 304; }
    else if (lvl == 3) { feat = p3; H = 100; W = 152; }
    else if (lvl == 4) { feat = p4; H = 50;  W = 76;  }
    else               { feat = p5; H = 25;  W = 38;  }

    const float im_h  = im_info[0];
    const float scale = (float)H / im_h;
    const float x1 = x1r * scale, y1 = y1r * scale;
    const float x2 = x2r * scale, y2 = y2r * scale;
    const float rw = fmaxf(x2 - x1, 1.f);
    const float rh = fmaxf(y2 - y1, 1.f);
    const float bh = rh * (1.f / 7.f);
    const float bw = rw * (1.f / 7.f);

    if (tid < 28) {
        if (tid < 14) {
            int i = tid, pi = i >> 1, s = i & 1;
            float ys = y1 + pi * bh + (s + 0.5f) * bh * 0.5f;
            float v  = (ys >= -1.f && ys <= (float)H) ? 1.f : 0.f;
            float yc = fminf(fmaxf(ys, 0.f), (float)H - 1.f);
            int y0 = (int)floorf(yc);
            s_y0[i] = y0; s_y1[i] = min(y0 + 1, H - 1);
            s_ly[i] = yc - (float)y0; s_vy[i] = v;
        } else {
            int i = tid - 14, pi = i >> 1, s = i & 1;
            float xs = x1 + pi * bw + (s + 0.5f) * bw * 0.5f;
            float v  = (xs >= -1.f && xs <= (float)W) ? 1.f : 0.f;
            float xc = fminf(fmaxf(xs, 0.f), (float)W - 1.f);
            int x0 = (int)floorf(xc);
            s_x0[i] = x0; s_x1[i] = min(x0 + 1, W - 1);
            s_lx[i] = xc - (float)x0; s_vx[i] = v;
        }
    }
    __syncthreads();

    const int b  = (int)bx;
    const int cg = tid & 63;        // channel group: channels cg*4 .. cg*4+3
    const int bg = tid >> 6;        // bin phase 0..3
    const ushort* fc = feat + (size_t)b * H * W * 256 + cg * 4;

    for (int bin = bg; bin < 49; bin += 4) {
        const int py = bin / 7, px = bin - (bin / 7) * 7;
        f32x4 acc = {0.f, 0.f, 0.f, 0.f};
        #pragma unroll
        for (int sy = 0; sy < 2; ++sy) {
            #pragma unroll
            for (int sx = 0; sx < 2; ++sx) {
                const int iy = py * 2 + sy, ix = px * 2 + sx;
                const float ly = s_ly[iy], lx = s_lx[ix];
                const float hy = 1.f - ly, hx = 1.f - lx;
                const int y0 = s_y0[iy], y1i = s_y1[iy];
                const int x0 = s_x0[ix], x1i = s_x1[ix];
                const float vf  = s_vy[iy] * s_vx[ix];
                const float w00 = hy * hx * vf, w01 = hy * lx * vf;
                const float w10 = ly * hx * vf, w11 = ly * lx * vf;
                ushort4 u00 = *(const ushort4*)&fc[(size_t)(y0 * W + x0) * 256];
                ushort4 u01 = *(const ushort4*)&fc[(size_t)(y0 * W + x1i) * 256];
                ushort4 u10 = *(const ushort4*)&fc[(size_t)(y1i * W + x0) * 256];
                ushort4 u11 = *(const ushort4*)&fc[(size_t)(y1i * W + x1i) * 256];
                acc[0] += w00 * bf2f(u00.x) + w01 * bf2f(u01.x) + w10 * bf2f(u10.x) + w11 * bf2f(u11.x);
                acc[1] += w00 * bf2f(u00.y) + w01 * bf2f(u01.y) + w10 * bf2f(u10.y) + w11 * bf2f(u11.y);
                acc[2] += w00 * bf2f(u00.z) + w01 * bf2f(u01.z) + w10 * bf2f(u10.z) + w11 * bf2f(u11.z);
                acc[3] += w00 * bf2f(u00.w) + w01 * bf2f(u01.w) + w10 * bf2f(u10.w) + w11 * bf2f(u11.w);
            }
        }
        acc[0] *= 0.25f; acc[1] *= 0.25f; acc[2] *= 0.25f; acc[3] *= 0.25f;
        *(f32x4*)&s_o[bin * 260 + cg * 4] = acc;
    }
    __syncthreads();

    // coalesced output: out flat index j = c*49 + bin  (out[r][256][7][7])
    float* orow = out + (size_t)r * 256 * 49;
    for (int it = 0; it < 49; ++it) {
        int j  = it * 256 + tid;
        int c  = j / 49;
        int bq = j - c * 49;
        orow[j] = s_o[bq * 260 + c];
    }
}

static inline int cdiv(int a, int b) { return (a + b - 1) / b; }

extern "C" void kernel_launch(void* const* d_in, const int* in_sizes, int n_in,
                              void* d_out, int out_size, void* d_ws, size_t ws_size,
                              hipStream_t stream) {
    const float* c2      = (const float*)d_in[0];
    const float* c3      = (const float*)d_in[1];
    const float* c4      = (const float*)d_in[2];
    const float* c5      = (const float*)d_in[3];
    const float* rois    = (const float*)d_in[4];
    const float* im_info = (const float*)d_in[5];
    const float* w_top   = (const float*)d_in[6];
    const float* b_top   = (const float*)d_in[7];
    const float* w_lat1  = (const float*)d_in[8];
    const float* b_lat1  = (const float*)d_in[9];
    const float* w_lat2  = (const float*)d_in[10];
    const float* b_lat2  = (const float*)d_in[11];
    const float* w_lat3  = (const float*)d_in[12];
    const float* b_lat3  = (const float*)d_in[13];
    const float* w_sm1   = (const float*)d_in[14];
    const float* b_sm1   = (const float*)d_in[15];
    const float* w_sm2   = (const float*)d_in[16];
    const float* b_sm2   = (const float*)d_in[17];
    const float* w_sm3   = (const float*)d_in[18];
    const float* b_sm3   = (const float*)d_in[19];
    float* out = (float*)d_out;
    ushort* ws = (ushort*)d_ws;

    // workspace layout (bf16 elements, all 16B-aligned). Per-level padded T
    // buffers (borders zeroed once, up front). p2 aliases c2t (dead by then).
    ushort* c2t = ws;                      // 2*60800*256  = 31129600
    ushort* c3t = c2t + 31129600;          // 2*15200*512  = 15564800
    ushort* c4t = c3t + 15564800;          // 2*3800*1024  = 7782400
    ushort* c5t = c4t + 7782400;           // 2*950*2048   = 3891200
    ushort* p5  = c5t + 3891200;           // 2*950*256    = 486400
    ushort* p4  = p5  + 486400;            // 2*3800*256   = 1945600
    ushort* p3  = p4  + 1945600;           // 2*15200*256  = 7782400
    ushort* T2  = p3  + 7782400;           // 2*202*306*256 = 31647744
    ushort* T3  = T2  + 31647744;          // 2*102*154*256 = 8042496
    ushort* T4  = T3  + 8042496;           // 2*52*78*256   = 2076672
    ushort* wtp = T4  + 2076672;           // 524288
    ushort* wl1 = wtp + 524288;            // 262144
    ushort* wl2 = wl1 + 262144;            // 131072
    ushort* wl3 = wl2 + 131072;            // 65536
    ushort* ws1 = wl3 + 65536;             // 589824
    ushort* ws2 = ws1 + 589824;            // 589824
    ushort* ws3 = ws2 + 589824;            // 589824
    ushort* p2  = c2t;                     // alias (c2t consumed before p2 write)

    dim3 blk(256);

    // 1: all weight packs + all border zeros
    pack_zero_k<<<dim3(2304, 10), blk, 0, stream>>>(
        w_top, w_lat1, w_lat2, w_lat3, w_sm1, w_sm2, w_sm3,
        wtp, wl1, wl2, wl3, ws1, ws2, ws3, T4, T3, T2);

    // 2: all input transposes
    nchw2nhwc_all<<<dim3(3566, 1, 2), blk, 0, stream>>>(
        c2, c3, c4, c5, c2t, c3t, c4t, c5t);

    // 3: p5 = conv1x1(c5)
    conv1_mfma<0><<<dim3(16, 1, 2), blk, 0, stream>>>(c5t, wtp, b_top, p5, (const ushort*)0, 2048, 25, 38, 8);

    // 4-5: level 4 (lat+upsample fused -> padded T4, 3x3 -> p4)
    conv1_mfma<1><<<dim3(60, 1, 2), blk, 0, stream>>>(c4t, wl1, b_lat1, T4, p5, 1024, 50, 76, 30);
    conv3_mfma<<<dim3(70, 1, 2), blk, 0, stream>>>(T4, ws1, b_sm1, p4, 50, 76, 5, 35);

    // 6-7: level 3
    conv1_mfma<1><<<dim3(238, 1, 2), blk, 0, stream>>>(c3t, wl2, b_lat2, T3, p4, 512, 100, 152, 119);
    conv3_mfma<<<dim3(260, 1, 2), blk, 0, stream>>>(T3, ws2, b_sm2, p3, 100, 152, 10, 130);

    // 8-9: level 2
    conv1_mfma<1><<<dim3(950, 1, 2), blk, 0, stream>>>(c2t, wl3, b_lat3, T2, p3, 256, 200, 304, 475);
    conv3_mfma<<<dim3(950, 1, 2), blk, 0, stream>>>(T2, ws3, b_sm3, p2, 200, 304, 19, 475);

    // 10: roi align
    roi_align_k<<<dim3(1024), blk, 0, stream>>>(rois, im_info, p2, p3, p4, p5, out);
}